// Round 3
// baseline (119.378 us; speedup 1.0000x reference)
//
#include <hip/hip_runtime.h>
#include <math.h>

#define NCELLS (64 * 128 * 128)            // 1,048,576
#define BLOCK 256
#define CELLS_PER_BLOCK 1024
#define GRID (NCELLS / CELLS_PER_BLOCK)    // 1024 blocks
#define CELLS_PER_THREAD (CELLS_PER_BLOCK / BLOCK)  // 4
#define NACC 6
#define EPSV 1e-10f

// ws layout (zeroed by 32B memset each launch):
// [0..5] float accumulators {m, s_noobj, s_nresp, s_xy, s_wh, s_obj}
// [6]    finished-block counter (uint)

__device__ __forceinline__ float sigmoidf_(float x) {
    return 1.0f / (1.0f + __expf(-x));
}
__device__ __forceinline__ float softplusf_(float x) {
    // logaddexp(0,x) = max(x,0) + log(1 + exp(-|x|))
    return fmaxf(x, 0.0f) + __logf(1.0f + __expf(-fabsf(x)));
}
__device__ __forceinline__ float iou_(float cx, float cy, float cw, float ch,
                                      float tx, float ty, float tw, float th) {
    float plx = cx - 0.5f * cw, ply = cy - 0.5f * ch;
    float prx = cx + 0.5f * cw, pry = cy + 0.5f * ch;
    float tlx = tx - 0.5f * tw, tly = ty - 0.5f * th;
    float trx = tx + 0.5f * tw, try_ = ty + 0.5f * th;
    float wx = fmaxf(fminf(prx, trx) - fmaxf(plx, tlx), 0.0f);
    float wy = fmaxf(fminf(pry, try_) - fmaxf(ply, tly), 0.0f);
    float inter = wx * wy;
    return inter / (cw * ch + tw * th - inter + EPSV);
}

__global__ __launch_bounds__(BLOCK) void yolo_fused_kernel(
        const float4* __restrict__ in4,
        const float4* __restrict__ tg4,
        float* __restrict__ ws,
        float* __restrict__ out) {
    // LDS staging: perfectly coalesced global loads (1 KB/instr/wave), then
    // cheap scalar LDS reads (stride 10 / 5 dwords -> 2-way aliasing = free).
    __shared__ float lds_in[CELLS_PER_BLOCK * 10];   // 40 KB
    __shared__ float lds_tg[CELLS_PER_BLOCK * 5];    // 20 KB -> 60 KB total, 2 blocks/CU

    const int t = threadIdx.x;
    {
        float4* li = (float4*)lds_in;
        const float4* __restrict__ gp = in4 + (size_t)blockIdx.x * (CELLS_PER_BLOCK * 10 / 4);
        #pragma unroll
        for (int k = 0; k < 10; ++k) li[k * BLOCK + t] = gp[k * BLOCK + t];
        float4* lt = (float4*)lds_tg;
        const float4* __restrict__ tp = tg4 + (size_t)blockIdx.x * (CELLS_PER_BLOCK * 5 / 4);
        #pragma unroll
        for (int k = 0; k < 5; ++k) lt[k * BLOCK + t] = tp[k * BLOCK + t];
    }
    __syncthreads();

    float m_cnt = 0.0f, s_noobj = 0.0f, s_nresp = 0.0f;
    float s_xy = 0.0f, s_wh = 0.0f, s_obj = 0.0f;

    #pragma unroll
    for (int j = 0; j < CELLS_PER_THREAD; ++j) {
        int c = j * BLOCK + t;
        const float* f = lds_in + c * 10;  // [logit0, x0,y0,w0,h0, logit1, x1,y1,w1,h1]
        const float* tt = lds_tg + c * 5;  // [conf, tx,ty,tw,th]

        float logit0 = f[0], logit1 = f[5];
        float bce0_0 = softplusf_(logit0);
        float bce0_1 = softplusf_(logit1);

        float tx = tt[1], ty = tt[2], tw = tt[3], th = tt[4];
        bool obj = (tt[0] > 0.0f);

        if (!obj) {
            s_noobj += bce0_0 + bce0_1;
        } else {
            m_cnt += 1.0f;
            float cx0 = sigmoidf_(f[1]), cy0 = sigmoidf_(f[2]);
            float cw0 = sigmoidf_(f[3]), ch0 = sigmoidf_(f[4]);
            float cx1 = sigmoidf_(f[6]), cy1 = sigmoidf_(f[7]);
            float cw1 = sigmoidf_(f[8]), ch1 = sigmoidf_(f[9]);

            float iou0 = iou_(cx0, cy0, cw0, ch0, tx, ty, tw, th);
            float iou1 = iou_(cx1, cy1, cw1, ch1, tx, ty, tw, th);
            bool r1 = (iou1 > iou0);   // argmax first-index tie-break

            float rcx = r1 ? cx1 : cx0, rcy = r1 ? cy1 : cy0;
            float rcw = r1 ? cw1 : cw0, rch = r1 ? ch1 : ch0;
            float dx = rcx - tx, dy = rcy - ty;
            float dw = rcw - tw, dh = rch - th;
            s_xy += dx * dx + dy * dy;
            s_wh += dw * dw + dh * dh;
            s_obj += r1 ? (bce0_1 - logit1) : (bce0_0 - logit0);
            s_nresp += r1 ? bce0_0 : bce0_1;
        }
    }

    // 64-lane butterfly reduce, then cross-wave via LDS
    float vals[NACC] = {m_cnt, s_noobj, s_nresp, s_xy, s_wh, s_obj};
    #pragma unroll
    for (int i = 0; i < NACC; ++i) {
        float v = vals[i];
        #pragma unroll
        for (int off = 32; off > 0; off >>= 1) v += __shfl_down(v, off, 64);
        vals[i] = v;
    }

    __shared__ float sm[4][NACC];
    int wave = t >> 6, lane = t & 63;
    if (lane == 0) {
        #pragma unroll
        for (int i = 0; i < NACC; ++i) sm[wave][i] = vals[i];
    }
    __syncthreads();

    // block partials -> global accumulators (device-scope atomics)
    if (t < NACC) {
        float s = sm[0][t] + sm[1][t] + sm[2][t] + sm[3][t];
        atomicAdd(&ws[t], s);
    }
    // __syncthreads drains vmcnt -> the 6 atomicAdds are performed at the
    // coherent point before the counter increments (see m97 asm: compiler
    // emits s_waitcnt vmcnt(0) before s_barrier).
    __syncthreads();

    __shared__ unsigned is_last;
    if (t == 0) {
        __threadfence();
        unsigned old = atomicAdd((unsigned*)&ws[NACC], 1u);
        is_last = (old == GRID - 1) ? 1u : 0u;
    }
    __syncthreads();

    if (is_last && t == 0) {
        __threadfence();
        // coherent reads of the accumulators
        float m       = atomicAdd(&ws[0], 0.0f);
        float s_no    = atomicAdd(&ws[1], 0.0f);
        float s_nr    = atomicAdd(&ws[2], 0.0f);
        float sxy     = atomicAdd(&ws[3], 0.0f);
        float swh     = atomicAdd(&ws[4], 0.0f);
        float sob     = atomicAdd(&ws[5], 0.0f);

        float n_noobj = (float)NCELLS - m;
        float loss_noobj = s_no / (n_noobj * 2.0f) + s_nr / m;  // B=2 -> (B-1)=1
        float loss_xy = sxy / (m * 2.0f);
        float loss_wh = swh / (m * 2.0f);
        float loss_obj = sob / m;
        out[0] = loss_noobj + loss_xy + loss_wh + loss_obj;
        out[1] = loss_noobj;
        out[2] = loss_xy;
        out[3] = loss_wh;
        out[4] = loss_obj;
    }
}

extern "C" void kernel_launch(void* const* d_in, const int* in_sizes, int n_in,
                              void* d_out, int out_size, void* d_ws, size_t ws_size,
                              hipStream_t stream) {
    const float4* in4 = (const float4*)d_in[0];
    const float4* tg4 = (const float4*)d_in[1];
    float* out = (float*)d_out;
    float* ws = (float*)d_ws;

    // zero the 6 accumulators + finished counter (32 B) — legal graph memset node
    hipMemsetAsync(ws, 0, 32, stream);
    hipLaunchKernelGGL(yolo_fused_kernel, dim3(GRID), dim3(BLOCK), 0, stream,
                       in4, tg4, ws, out);
}